// Round 5
// baseline (314.154 us; speedup 1.0000x reference)
//
#include <hip/hip_runtime.h>

// MultiScaleSubsequenceExtractor: masked sliding-window means.
// B=128, L=1024, D=128, windows {4,8,16,32}; out rows/batch = 1021+1017+1009+993 = 4040.
// Steady-state HBM/iter: ~64 MB read (poison fills cycle L3 between iterations, so the
// input can NOT stay L3-resident) + 265 MB write -> ~52 us kernel floor at 6.3 TB/s.
// Ladder (kernel est. = bench - ~233 us fixed fill/graph overhead):
//  R2: LDS-stage TILE=64, NT loads + NT stores        ~80 us (bench 313)
//  R4: cached loads + PLAIN stores + swizzle           ~94 us (bench 327)
//  R5: no-LDS streaming                                ~148 us (latency-bound, dead)
//  R6: cached loads + NT stores                        ~74 us (bench 307)  <- base
// R7: T14 async-stage split. Block owns 128 positions = 2 tiles. Tile B's 64 fresh rows
//     are issued as register loads BEFORE tile A's compute (HBM latency hides under A's
//     compute+stores), ds-written into a 96-row LDS ring after A finishes reading.
//     Read amp 1.5x -> 1.25x; A-side stores unconditional. Flavors unchanged vs R6.

namespace {
constexpr int kB    = 128;
constexpr int kL    = 1024;
constexpr int kD    = 128;
constexpr int kD4   = kD / 4;        // float4 per row = 32
constexpr int BPOS  = 128;           // positions per block (2 tiles of 64)
constexpr int HALO  = 32;
constexpr int RING  = 64 + HALO;     // 96-row LDS ring
constexpr int ROUT  = 4040;          // output rows per batch
constexpr int OFF4  = 0;
constexpr int OFF8  = 1021;
constexpr int OFF16 = 2038;          // 1021 + 1017
constexpr int OFF32 = 3047;          // 2038 + 1009
}

typedef float v4f __attribute__((ext_vector_type(4)));

__device__ __forceinline__ void nt_store(float4* p, const float4& v) {
    v4f x;
    x.x = v.x; x.y = v.y; x.z = v.z; x.w = v.w;
    __builtin_nontemporal_store(x, reinterpret_cast<v4f*>(p));
}
__device__ __forceinline__ float4 f4zero() { return make_float4(0.f, 0.f, 0.f, 0.f); }

__device__ __forceinline__ void acc4(float4& a, const float4& x) {
    a.x += x.x; a.y += x.y; a.z += x.z; a.w += x.w;
}
__device__ __forceinline__ void slide4(float4& a, const float4& xin, const float4& xout) {
    a.x += xin.x - xout.x; a.y += xin.y - xout.y;
    a.z += xin.z - xout.z; a.w += xin.w - xout.w;
}
__device__ __forceinline__ float4 scale4(const float4& v, float s) {
    return make_float4(v.x * s, v.y * s, v.z * s, v.w * s);
}

__global__ __launch_bounds__(256)
void msse_kernel(const float* __restrict__ emb,
                 const int*   __restrict__ mask,
                 float*       __restrict__ out) {
    __shared__ float4 s_data[RING * kD4];   // 48 KB ring of masked rows
    __shared__ float  s_maskf[BPOS + HALO]; // 160 mask floats, rows [P0, P0+160)
    __shared__ float  s_inv[4][BPOS];       // 1/clip(count,1) per window per position

    const int b  = blockIdx.y;
    const int P0 = blockIdx.x * BPOS;       // 0,128,...,896
    const int t  = threadIdx.x;

    const float4* gsrc = reinterpret_cast<const float4*>(emb) + (size_t)b * kL * kD4;

    // ---- mask floats for all 160 rows this block touches ----
    if (t < BPOS + HALO) {
        const int row = P0 + t;
        s_maskf[t] = (row < kL) ? (float)mask[b * kL + row] : 0.f;
    }

    // ---- stage tile A rows [P0, P0+96) into ring slots [0,96), masked, coalesced ----
    // (P0+95 <= 991 < kL always: no guard needed)
    #pragma unroll
    for (int k = 0; k < (RING * kD4) / 256; ++k) {   // 12 iters
        const int f    = t + k * 256;
        const int row  = f >> 5;                     // 0..95
        const int grow = P0 + row;
        const float m  = (float)mask[b * kL + grow];
        float4 v = gsrc[(size_t)grow * kD4 + (f & 31)];
        v.x *= m; v.y *= m; v.z *= m; v.w *= m;
        s_data[f] = v;
    }
    __syncthreads();

    // ---- issue tile B's fresh rows [P0+96, P0+160) into REGISTERS now; the loads'
    //      latency hides under tile A's compute+stores below (T14 async-stage split) ----
    float4 pf0, pf1, pf2, pf3, pf4, pf5, pf6, pf7;
    {
        const int f  = t;                 // k-th chunk: f + k*256
        #define PF(K, DST)                                                        \
        {                                                                         \
            const int ff   = f + (K) * 256;                                       \
            const int grow = P0 + 96 + (ff >> 5);                                 \
            DST = (grow < kL) ? gsrc[(size_t)grow * kD4 + (ff & 31)] : f4zero();  \
        }
        PF(0, pf0) PF(1, pf1) PF(2, pf2) PF(3, pf3)
        PF(4, pf4) PF(5, pf5) PF(6, pf6) PF(7, pf7)
        #undef PF
    }

    // ---- per-position window-count reciprocals for all 128 positions ----
    if (t < BPOS) {
        float c = 0.f, c4 = 0.f, c8 = 0.f, c16 = 0.f;
        #pragma unroll
        for (int j = 0; j < 32; ++j) {
            c += s_maskf[t + j];
            if (j == 3)  c4  = c;
            if (j == 7)  c8  = c;
            if (j == 15) c16 = c;
        }
        s_inv[0][t] = 1.f / fmaxf(c4,  1.f);
        s_inv[1][t] = 1.f / fmaxf(c8,  1.f);
        s_inv[2][t] = 1.f / fmaxf(c16, 1.f);
        s_inv[3][t] = 1.f / fmaxf(c,   1.f);
    }
    __syncthreads();

    const int lane  = t & 31;        // float4 column
    const int strip = t >> 5;        // 0..7
    const float4* col = s_data + lane;
    float4* outb = reinterpret_cast<float4*>(out) + (size_t)b * ROUT * kD4 + lane;

    // ================= tile A: positions [P0, P0+64), ring rows 0..95 direct =========
    {
        const int base = strip * 8;
        float4 s4, s8, s16, s32;
        {
            float4 a = f4zero(), t4 = a, t8 = a, t16 = a;
            #pragma unroll
            for (int j = 0; j < 32; ++j) {
                acc4(a, col[(base + j) * kD4]);
                if (j == 3)  t4  = a;
                if (j == 7)  t8  = a;
                if (j == 15) t16 = a;
            }
            s4 = t4; s8 = t8; s16 = t16; s32 = a;
        }
        #pragma unroll
        for (int p = 0; p < 8; ++p) {
            const int il = base + p;          // 0..63
            const int i  = P0 + il;           // <= 959: all four stores in-bounds
            nt_store(outb + (size_t)(OFF4  + i) * kD4, scale4(s4,  s_inv[0][il]));
            nt_store(outb + (size_t)(OFF8  + i) * kD4, scale4(s8,  s_inv[1][il]));
            nt_store(outb + (size_t)(OFF16 + i) * kD4, scale4(s16, s_inv[2][il]));
            nt_store(outb + (size_t)(OFF32 + i) * kD4, scale4(s32, s_inv[3][il]));
            const float4 x0 = col[(il)      * kD4];
            const float4 xa = col[(il + 4)  * kD4];
            const float4 xb = col[(il + 8)  * kD4];
            const float4 xc = col[(il + 16) * kD4];
            const float4 xd = col[(il + 32) * kD4];
            slide4(s4,  xa, x0);
            slide4(s8,  xb, x0);
            slide4(s16, xc, x0);
            slide4(s32, xd, x0);
        }
    }
    __syncthreads();   // all tile-A LDS reads complete before ring overwrite

    // ---- land prefetched rows: ring slots [0,64) <- rows [P0+96, P0+160), masked ----
    {
        #define WR(K, SRC)                                                \
        {                                                                 \
            const int ff = t + (K) * 256;                                 \
            const float m = s_maskf[96 + (ff >> 5)];                      \
            float4 v = SRC;                                               \
            v.x *= m; v.y *= m; v.z *= m; v.w *= m;                       \
            s_data[ff] = v;                                               \
        }
        WR(0, pf0) WR(1, pf1) WR(2, pf2) WR(3, pf3)
        WR(4, pf4) WR(5, pf5) WR(6, pf6) WR(7, pf7)
        #undef WR
    }
    __syncthreads();

    // ================= tile B: positions [P0+64, P0+128), ring rows 64..159 ==========
    {
        const int base = 64 + strip * 8;      // local position 64..120
        // ring row -> LDS slot
        auto ldrow = [&](int r) -> const float4& {
            const int sl = (r >= RING) ? (r - RING) : r;
            return col[sl * kD4];
        };
        float4 s4, s8, s16, s32;
        {
            float4 a = f4zero(), t4 = a, t8 = a, t16 = a;
            #pragma unroll
            for (int j = 0; j < 32; ++j) {
                acc4(a, ldrow(base + j));     // rows 64..151
                if (j == 3)  t4  = a;
                if (j == 7)  t8  = a;
                if (j == 15) t16 = a;
            }
            s4 = t4; s8 = t8; s16 = t16; s32 = a;
        }
        #pragma unroll
        for (int p = 0; p < 8; ++p) {
            const int il = base + p;          // 64..127
            const int i  = P0 + il;           // up to 1023: guards needed
            if (i <= kL - 4)  nt_store(outb + (size_t)(OFF4  + i) * kD4, scale4(s4,  s_inv[0][il]));
            if (i <= kL - 8)  nt_store(outb + (size_t)(OFF8  + i) * kD4, scale4(s8,  s_inv[1][il]));
            if (i <= kL - 16) nt_store(outb + (size_t)(OFF16 + i) * kD4, scale4(s16, s_inv[2][il]));
            if (i <= kL - 32) nt_store(outb + (size_t)(OFF32 + i) * kD4, scale4(s32, s_inv[3][il]));
            const float4 x0 = ldrow(il);
            const float4 xa = ldrow(il + 4);
            const float4 xb = ldrow(il + 8);
            const float4 xc = ldrow(il + 16);
            const float4 xd = ldrow(il + 32);   // rows up to 159
            slide4(s4,  xa, x0);
            slide4(s8,  xb, x0);
            slide4(s16, xc, x0);
            slide4(s32, xd, x0);
        }
    }
}

extern "C" void kernel_launch(void* const* d_in, const int* in_sizes, int n_in,
                              void* d_out, int out_size, void* d_ws, size_t ws_size,
                              hipStream_t stream) {
    const float* emb  = (const float*)d_in[0];
    const int*   mask = (const int*)d_in[1];
    float*       out  = (float*)d_out;

    dim3 grid(kL / BPOS, kB);   // (8, 128) = 1024 blocks, 3/CU
    dim3 block(256);
    msse_kernel<<<grid, block, 0, stream>>>(emb, mask, out);
}

// Round 6
// 309.276 us; speedup vs baseline: 1.0158x; 1.0158x over previous
//
#include <hip/hip_runtime.h>

// MultiScaleSubsequenceExtractor: masked sliding-window means.
// B=128, L=1024, D=128, windows {4,8,16,32}; out rows/batch = 1021+1017+1009+993 = 4040.
// Steady-state HBM/iter: ~64 MB read + 265 MB write -> ~52 us kernel floor at 6.3 TB/s
// (m13: mixed read/write streams DO reach 6.29 TB/s, so the floor is real).
// Ladder (kernel est. = bench - ~233 us fixed fill/graph overhead):
//  R2: LDS-stage TILE=64, NT loads + NT stores        ~80 us (bench 313)
//  R4: cached loads + PLAIN stores + swizzle           ~94 us (bench 327)
//  R5: no-LDS streaming                                ~148 us (latency-bound, dead)
//  R6: cached loads + NT stores                        ~74 us (bench 307)  <- base
//  R7: 2-tile ring + reg prefetch (T14)                ~81 us (bench 314; ring-wrap
//      VALU on every LDS read + extra barrier ate the overlap gain)
// R8: stage via __builtin_amdgcn_global_load_lds width=16 (direct HBM->LDS, no VGPR
//     round trip, 12 loads fully in flight) + mask-at-read (slide4m: same op count as
//     slide4; OOB rows clamp the ADDRESS, mask=0 kills the value). Only the staging
//     path changes vs R6.

namespace {
constexpr int kB    = 128;
constexpr int kL    = 1024;
constexpr int kD    = 128;
constexpr int kD4   = kD / 4;        // float4 per row = 32
constexpr int TILE  = 64;            // output positions per block
constexpr int HALO  = 32;            // max window size
constexpr int ROWS  = TILE + HALO;   // 96 staged rows
constexpr int ROUT  = 4040;          // output rows per batch
constexpr int OFF4  = 0;
constexpr int OFF8  = 1021;
constexpr int OFF16 = 2038;          // 1021 + 1017
constexpr int OFF32 = 3047;          // 2038 + 1009
}

typedef float v4f __attribute__((ext_vector_type(4)));
#define AS_GLOBAL __attribute__((address_space(1)))
#define AS_LDS    __attribute__((address_space(3)))

__device__ __forceinline__ void nt_store(float4* p, const float4& v) {
    v4f x;
    x.x = v.x; x.y = v.y; x.z = v.z; x.w = v.w;
    __builtin_nontemporal_store(x, reinterpret_cast<v4f*>(p));
}
__device__ __forceinline__ float4 f4zero() { return make_float4(0.f, 0.f, 0.f, 0.f); }

// a += x * m
__device__ __forceinline__ void fma4(float4& a, const float4& x, float m) {
    a.x = fmaf(x.x, m, a.x); a.y = fmaf(x.y, m, a.y);
    a.z = fmaf(x.z, m, a.z); a.w = fmaf(x.w, m, a.w);
}
// a += xi*mi - xo*mo   (2 FMA per component == slide4's add+sub cost)
__device__ __forceinline__ void slide4m(float4& a, const float4& xi, float mi,
                                        const float4& xo, float mo) {
    a.x = fmaf(xi.x, mi, fmaf(-xo.x, mo, a.x));
    a.y = fmaf(xi.y, mi, fmaf(-xo.y, mo, a.y));
    a.z = fmaf(xi.z, mi, fmaf(-xo.z, mo, a.z));
    a.w = fmaf(xi.w, mi, fmaf(-xo.w, mo, a.w));
}
__device__ __forceinline__ float4 scale4(const float4& v, float s) {
    return make_float4(v.x * s, v.y * s, v.z * s, v.w * s);
}

__global__ __launch_bounds__(256)
void msse_kernel(const float* __restrict__ emb,
                 const int*   __restrict__ mask,
                 float*       __restrict__ out) {
    __shared__ float4 s_data[ROWS * kD4];   // 48 KB: RAW (unmasked) embedding rows
    __shared__ float  s_maskf[ROWS];
    __shared__ float  s_inv[4][TILE];       // 1/clip(count,1) per window per position

    const int b  = blockIdx.y;
    const int i0 = blockIdx.x * TILE;
    const int t  = threadIdx.x;

    const float4* gsrc = reinterpret_cast<const float4*>(emb) + (size_t)b * kL * kD4;

    // ---- stage rows [i0, i0+96) direct HBM->LDS: 12 x global_load_lds(16B)/thread,
    //      no VGPR round trip, all 12 in flight. LDS slot f = t + k*256 is linear per
    //      wave => dest = wave-uniform base + lane*16 as the HW requires.
    {
        const int wb = t & ~63;                       // wave-uniform LDS base (float4 idx)
        #pragma unroll
        for (int k = 0; k < (ROWS * kD4) / 256; ++k) {   // 12 iters
            const int f  = t + k * 256;
            int grow = i0 + (f >> 5);
            grow = (grow < kL) ? grow : (kL - 1);     // clamp addr; value killed by m=0
            const float4* gp = gsrc + (size_t)grow * kD4 + (f & 31);
            float4*       lp = s_data + k * 256 + wb;
            __builtin_amdgcn_global_load_lds((const AS_GLOBAL void*)gp,
                                             (AS_LDS void*)lp, 16, 0, 0);
        }
    }

    // ---- mask floats for the 96 staged rows (loads land under the staging flight) ----
    if (t < ROWS) {
        const int row = i0 + t;
        s_maskf[t] = (row < kL) ? (float)mask[b * kL + row] : 0.f;
    }
    __syncthreads();   // drains vmcnt (LDS-direct loads) + lgkm (s_maskf)

    // ---- per-position window-count reciprocals (threads 0..63) ----
    if (t < TILE) {
        float c = 0.f, c4 = 0.f, c8 = 0.f, c16 = 0.f;
        #pragma unroll
        for (int j = 0; j < 32; ++j) {
            c += s_maskf[t + j];
            if (j == 3)  c4  = c;
            if (j == 7)  c8  = c;
            if (j == 15) c16 = c;
        }
        s_inv[0][t] = 1.f / fmaxf(c4,  1.f);
        s_inv[1][t] = 1.f / fmaxf(c8,  1.f);
        s_inv[2][t] = 1.f / fmaxf(c16, 1.f);
        s_inv[3][t] = 1.f / fmaxf(c,   1.f);
    }
    __syncthreads();

    // ---- sliding-window sums: thread = (float4 column, 8-position strip) ----
    const int lane  = t & 31;        // float4 column index
    const int strip = t >> 5;        // 0..7
    const int base  = strip * 8;     // first local position of strip

    const float4* col = s_data + lane;   // row stride = kD4

    float4 s4, s8, s16, s32;
    {
        float4 a = f4zero(), t4 = a, t8 = a, t16 = a;
        #pragma unroll
        for (int j = 0; j < 32; ++j) {
            fma4(a, col[(base + j) * kD4], s_maskf[base + j]);   // mask applied at read
            if (j == 3)  t4  = a;
            if (j == 7)  t8  = a;
            if (j == 15) t16 = a;
        }
        s4 = t4; s8 = t8; s16 = t16; s32 = a;
    }

    float4* outb = reinterpret_cast<float4*>(out) + (size_t)b * ROUT * kD4 + lane;

    #pragma unroll
    for (int p = 0; p < 8; ++p) {
        const int il = base + p;
        const int i  = i0 + il;

        if (i <= kL - 4)  nt_store(outb + (size_t)(OFF4  + i) * kD4, scale4(s4,  s_inv[0][il]));
        if (i <= kL - 8)  nt_store(outb + (size_t)(OFF8  + i) * kD4, scale4(s8,  s_inv[1][il]));
        if (i <= kL - 16) nt_store(outb + (size_t)(OFF16 + i) * kD4, scale4(s16, s_inv[2][il]));
        if (i <= kL - 32) nt_store(outb + (size_t)(OFF32 + i) * kD4, scale4(s32, s_inv[3][il]));

        // advance all windows to position i+1 (max row = base+7+32 = 95, in range)
        const float4 x0 = col[(il)      * kD4];  const float m0 = s_maskf[il];
        const float4 xa = col[(il + 4)  * kD4];  const float ma = s_maskf[il + 4];
        const float4 xb = col[(il + 8)  * kD4];  const float mb = s_maskf[il + 8];
        const float4 xc = col[(il + 16) * kD4];  const float mc = s_maskf[il + 16];
        const float4 xd = col[(il + 32) * kD4];  const float md = s_maskf[il + 32];
        slide4m(s4,  xa, ma, x0, m0);
        slide4m(s8,  xb, mb, x0, m0);
        slide4m(s16, xc, mc, x0, m0);
        slide4m(s32, xd, md, x0, m0);
    }
}

extern "C" void kernel_launch(void* const* d_in, const int* in_sizes, int n_in,
                              void* d_out, int out_size, void* d_ws, size_t ws_size,
                              hipStream_t stream) {
    const float* emb  = (const float*)d_in[0];
    const int*   mask = (const int*)d_in[1];
    float*       out  = (float*)d_out;

    dim3 grid((kL + TILE - 1) / TILE, kB);   // (16, 128) = 2048 blocks
    dim3 block(256);
    msse_kernel<<<grid, block, 0, stream>>>(emb, mask, out);
}